// Round 7
// baseline (542.506 us; speedup 1.0000x reference)
//
#include <hip/hip_runtime.h>
#include <math.h>

#define B_SZ 512
#define S_SZ 512
#define E_NUM 8
#define F_DIM 20
#define BM 16          // pairs per RNN block (full MFMA N-tile)
#define MAXBLK 71      // >= sum_e ceil(cnt_e/16) <= 71
#define SGRP 32        // xproj step-groups per pair-group
#define SSTEPS (S_SZ / SGRP)

typedef __attribute__((ext_vector_type(8))) short bf16x8;
typedef __attribute__((ext_vector_type(8))) _Float16 f16x8;
typedef __attribute__((ext_vector_type(4))) float f32x4;
typedef __attribute__((ext_vector_type(4))) unsigned int u32x4;
#define MFMA(a, b, c) __builtin_amdgcn_mfma_f32_16x16x32_bf16(a, b, c, 0, 0, 0)
#define MFMAH(a, b, c) __builtin_amdgcn_mfma_f32_16x16x32_f16(a, b, c, 0, 0, 0)

__device__ __forceinline__ unsigned short f2bf(float f) {  // RNE
  unsigned u = __float_as_uint(f);
  u += 0x7FFFu + ((u >> 16) & 1u);
  return (unsigned short)(u >> 16);
}
__device__ __forceinline__ float bf2f(unsigned short h) {
  return __uint_as_float(((unsigned)h) << 16);
}
// {a.hi16, b.hi16} -> one dword via v_perm_b32
__device__ __forceinline__ unsigned pack2_hi(float a, float b) {
  return __builtin_amdgcn_perm(__float_as_uint(b), __float_as_uint(a),
                               0x07060302u);
}
__device__ __forceinline__ float hi_f(float a) {
  return __uint_as_float(__float_as_uint(a) & 0xFFFF0000u);
}
// pack two f32 -> f16 pair (RNE) in one dword
__device__ __forceinline__ unsigned pk16(float a, float b) {
  _Float16 ha = (_Float16)a, hb = (_Float16)b;
  unsigned short ua = __builtin_bit_cast(unsigned short, ha);
  unsigned short ub = __builtin_bit_cast(unsigned short, hb);
  return (unsigned)ua | ((unsigned)ub << 16);
}
// 8 floats -> hi/lo bf16x8 via truncation split (x staging in xproj)
__device__ __forceinline__ void cvtX(const float4 a, const float4 b,
                                     bf16x8* hi, bf16x8* lo) {
  u32x4 h, l;
  h[0] = pack2_hi(a.x, a.y); h[1] = pack2_hi(a.z, a.w);
  h[2] = pack2_hi(b.x, b.y); h[3] = pack2_hi(b.z, b.w);
  l[0] = pack2_hi(a.x - hi_f(a.x), a.y - hi_f(a.y));
  l[1] = pack2_hi(a.z - hi_f(a.z), a.w - hi_f(a.w));
  l[2] = pack2_hi(b.x - hi_f(b.x), b.y - hi_f(b.y));
  l[3] = pack2_hi(b.z - hi_f(b.z), b.w - hi_f(b.w));
  *hi = *(bf16x8*)&h;
  *lo = *(bf16x8*)&l;
}
// 8 floats -> hi/lo bf16x8 via RNE split (one-time W_ih conversion)
__device__ __forceinline__ void cvt8r(float4 a, float4 b, bf16x8* hi, bf16x8* lo) {
  float v[8] = {a.x, a.y, a.z, a.w, b.x, b.y, b.z, b.w};
  bf16x8 h, l;
#pragma unroll
  for (int j = 0; j < 8; j++) {
    unsigned short hb = f2bf(v[j]);
    h[j] = (short)hb;
    l[j] = (short)f2bf(v[j] - bf2f(hb));
  }
  *hi = h; *lo = l;
}
__device__ __forceinline__ float ftanh(float x) {
  float e = __expf(x + x);  // x->+inf: e=inf -> rcp=0 -> 1; x->-inf: e=0 -> -1
  float r;
  asm("v_rcp_f32 %0, %1" : "=v"(r) : "v"(e + 1.0f));
  return fmaf(-2.0f, r, 1.0f);
}

// raw barrier: no compiler vmcnt(0) drain -> global prefetch stays in flight
#define BAR() do {                                        \
  asm volatile("s_waitcnt lgkmcnt(0)" ::: "memory");      \
  __builtin_amdgcn_s_barrier();                           \
  asm volatile("" ::: "memory");                          \
} while (0)

// ---------------- Kernel 0: one-time W_ih bf16 hi/lo split ----------------
__global__ __launch_bounds__(256) void k_wsplit(
    const float* __restrict__ W, unsigned short* __restrict__ Wh,
    unsigned short* __restrict__ Wl) {
  int idx = (blockIdx.x * 256 + threadIdx.x) * 8;  // 64 blocks cover 131072
  float4 a = *(const float4*)(W + idx);
  float4 b = *(const float4*)(W + idx + 4);
  bf16x8 h, l;
  cvt8r(a, b, &h, &l);
  *(bf16x8*)(Wh + idx) = h;
  *(bf16x8*)(Wl + idx) = l;
}

// ---------------- Kernel 1: x_mean + logits ----------------
__global__ __launch_bounds__(512) void k_mean_logits(
    const float* __restrict__ x, const float* __restrict__ w_gate,
    float* __restrict__ logits) {
  __shared__ float sm[512];
  __shared__ float xm[128];
  int b = blockIdx.x;
  int t = threadIdx.x;
  int i = t & 127, s0 = t >> 7;
  const float* xb = x + (size_t)b * (S_SZ * 128);
  float acc = 0.f;
  for (int s = s0; s < S_SZ; s += 4) acc += xb[s * 128 + i];
  sm[t] = acc;
  __syncthreads();
  if (t < 128)
    xm[t] = (sm[t] + sm[t + 128] + sm[t + 256] + sm[t + 384]) * (1.0f / 512.0f);
  __syncthreads();
  if (t < E_NUM) {
    float acc2 = 0.f;
    for (int ii = 0; ii < 128; ii++) acc2 += xm[ii] * w_gate[ii * E_NUM + t];
    logits[b * E_NUM + t] = acc2;
  }
}

// ------- Kernel 2: top-2 gates + CV^2 loss + expert compaction -------
__global__ __launch_bounds__(512) void k_gate(
    const float* __restrict__ logits, float* __restrict__ sel_g,
    int* __restrict__ pair_b, int* __restrict__ pair_of,
    int* __restrict__ blk_e, int* __restrict__ blk_p0,
    int* __restrict__ blk_nr, int* __restrict__ nblk,
    float* __restrict__ loss_out) {
  __shared__ float gmat[512][8];
  __shared__ int cnt[8], base[8], pos[8];
  __shared__ float imps[8];
  int t = threadIdx.x;
  if (t < 8) { cnt[t] = 0; pos[t] = 0; }
  float lv[8];
#pragma unroll
  for (int e = 0; e < 8; e++) {
    lv[e] = logits[t * 8 + e];
    gmat[t][e] = 0.f;
  }
  __syncthreads();
  float v0 = -INFINITY, v1 = -INFINITY;
  int i0 = 0, i1 = 0;
#pragma unroll
  for (int e = 0; e < 8; e++) {
    float v = lv[e];
    if (v > v0) { v1 = v0; i1 = i0; v0 = v; i0 = e; }
    else if (v > v1) { v1 = v; i1 = e; }
  }
  float ex = expf(v1 - v0);
  float inv = 1.0f / (1.0f + ex);
  float g0 = inv, g1 = ex * inv;
  gmat[t][i0] = g0;
  gmat[t][i1] = g1;
  atomicAdd(&cnt[i0], 1);
  atomicAdd(&cnt[i1], 1);
  sel_g[t * 2] = g0;
  sel_g[t * 2 + 1] = g1;
  __syncthreads();
  if (t == 0) {
    int o = 0;
    for (int e = 0; e < 8; e++) { base[e] = o; o += cnt[e]; }
    int nb = 0;
    for (int e = 0; e < 8; e++)
      for (int off = 0; off < cnt[e]; off += BM) {
        blk_e[nb] = e;
        blk_p0[nb] = base[e] + off;
        blk_nr[nb] = min(BM, cnt[e] - off);
        nb++;
      }
    *nblk = nb;
  }
  if (t < 8) {
    float s = 0.f;
    for (int bb = 0; bb < 512; bb++) s += gmat[bb][t];
    imps[t] = s;
  }
  __syncthreads();
  {
    int r = atomicAdd(&pos[i0], 1);
    int p = base[i0] + r;
    pair_b[p] = t;
    pair_of[t * 2] = p;
  }
  {
    int r = atomicAdd(&pos[i1], 1);
    int p = base[i1] + r;
    pair_b[p] = t;
    pair_of[t * 2 + 1] = p;
  }
  if (t == 0) {
    float mi = 0.f, ml = 0.f;
#pragma unroll
    for (int e = 0; e < 8; e++) { mi += imps[e]; ml += (float)cnt[e]; }
    mi *= 0.125f; ml *= 0.125f;
    float vi = 0.f, vl = 0.f;
#pragma unroll
    for (int e = 0; e < 8; e++) {
      float di = imps[e] - mi; vi += di * di;
      float dl = (float)cnt[e] - ml; vl += dl * dl;
    }
    vi *= (1.0f / 7.0f);
    vl *= (1.0f / 7.0f);
    loss_out[0] = 0.01f * (vi / (mi * mi + 1e-10f) + vl / (ml * ml + 1e-10f));
  }
}

// -------- Kernel 3a: x-projection GEMM -> P (fp32, workspace) --------
// P layout: [grp][s][hq(32)][pair(16)][4f32]; includes b_ih+b_hh.
// 8 waves x 1 M-tile; W from pre-split bf16 ws; 2 blocks/CU.
__global__ __launch_bounds__(512, 4) void k_xproj(
    const float* __restrict__ x, const unsigned short* __restrict__ Wh,
    const unsigned short* __restrict__ Wl, const float* __restrict__ b_ih,
    const float* __restrict__ b_hh, const int* __restrict__ pair_b,
    const int* __restrict__ blk_e, const int* __restrict__ blk_p0,
    const int* __restrict__ blk_nr, const int* __restrict__ nblk,
    float* __restrict__ P) {
  int grp = blockIdx.x >> 5, sgrp = blockIdx.x & 31;
  if (grp >= *nblk) return;
  int e = blk_e[grp], p0 = blk_p0[grp], nr = blk_nr[grp];
  int tid = threadIdx.x;
  int lane = tid & 63, g = lane >> 4, ln = lane & 15;
  int w = tid >> 6;  // M-tile 0..7
  int row = w * 16 + ln;

  bf16x8 wih_h[4], wih_l[4];
  const unsigned short* wb = Wh + (size_t)e * 16384 + row * 128 + g * 8;
  const unsigned short* wbl = Wl + (size_t)e * 16384 + row * 128 + g * 8;
#pragma unroll
  for (int ks = 0; ks < 4; ks++) {
    wih_h[ks] = *(const bf16x8*)(wb + ks * 32);
    wih_l[ks] = *(const bf16x8*)(wbl + ks * 32);
  }
  f32x4 biasv;
#pragma unroll
  for (int r = 0; r < 4; r++) {
    int h = w * 16 + g * 4 + r;
    biasv[r] = b_ih[e * 128 + h] + b_hh[e * 128 + h];
  }
  int bidx = pair_b[p0 + (ln < nr ? ln : 0)];
  const char* xlb = (const char*)x + (size_t)bidx * (S_SZ * 512) +
                    (size_t)sgrp * (SSTEPS * 512) + g * 32;
  float* Pb = P + ((size_t)grp * 512 + sgrp * SSTEPS) * 2048;
  int wo = (w * 4 + g) * 64 + ln * 4;

  float4 xr[8];
#pragma unroll 1
  for (int s = 0; s < SSTEPS; s++) {
#pragma unroll
    for (int j = 0; j < 8; j++)
      xr[j] = *(const float4*)(xlb + (size_t)s * 512 + (j >> 1) * 128 +
                               (j & 1) * 16);
    bf16x8 Xh[4], Xl[4];
#pragma unroll
    for (int ks = 0; ks < 4; ks++)
      cvtX(xr[2 * ks], xr[2 * ks + 1], &Xh[ks], &Xl[ks]);
    f32x4 pA = biasv;
#pragma unroll
    for (int ks = 0; ks < 4; ks++) pA = MFMA(wih_h[ks], Xh[ks], pA);
#pragma unroll
    for (int ks = 0; ks < 4; ks++) pA = MFMA(wih_l[ks], Xh[ks], pA);
#pragma unroll
    for (int ks = 0; ks < 4; ks++) pA = MFMA(wih_h[ks], Xl[ks], pA);
    *(f32x4*)(Pb + (size_t)s * 2048 + wo) = pA;
  }
}

// -------- Kernel 3b: recurrent MFMA RNN, f16 2-chain, 8 waves --------
// W_hh = Wh(f16) + 2^-10*Wl'(f16, pre-scaled x1024); H single f16 in LDS.
// Per wave-step: 4 ds_read_b128 + 1 global dwordx4 + 8 MFMA + 4 fma + tanh.
__global__ __launch_bounds__(512, 1) void k_rnn_p(
    const float* __restrict__ P, const float* __restrict__ W_hh,
    const float* __restrict__ fc1_w, const float* __restrict__ fc1_b,
    const float* __restrict__ fc2_w, const float* __restrict__ fc2_b,
    const int* __restrict__ blk_e, const int* __restrict__ blk_p0,
    const int* __restrict__ blk_nr, const int* __restrict__ nblk,
    float* __restrict__ outp) {
  __shared__ unsigned short sH[2][BM * 128];  // [parity] 16x128 f16 = 8 KB
  __shared__ float sZ[BM * F_DIM];

  int blk = blockIdx.x;
  if (blk >= *nblk) return;
  int e = blk_e[blk], p0 = blk_p0[blk], nr = blk_nr[blk];
  int tid = threadIdx.x;
  int lane = tid & 63, g = lane >> 4, ln = lane & 15;
  int w = tid >> 6;  // M-tile 0..7

  // ---- W_hh f16 2-split fragments (Wl pre-scaled x1024, no denormals) ----
  f16x8 wh[4], wl[4];
  {
    int row = w * 16 + ln;
    const float* bh = W_hh + (size_t)e * 16384 + row * 128 + g * 8;
#pragma unroll
    for (int ks = 0; ks < 4; ks++) {
      float4 a = *(const float4*)(bh + ks * 32);
      float4 b = *(const float4*)(bh + ks * 32 + 4);
      float v[8] = {a.x, a.y, a.z, a.w, b.x, b.y, b.z, b.w};
      f16x8 h, l;
#pragma unroll
      for (int j = 0; j < 8; j++) {
        _Float16 hh = (_Float16)v[j];
        h[j] = hh;
        l[j] = (_Float16)((v[j] - (float)hh) * 1024.0f);
      }
      wh[ks] = h;
      wl[ks] = l;
    }
  }
  // zero parity-0 H (4 KB)
  ((unsigned int*)sH)[tid] = 0;
  ((unsigned int*)sH)[tid + 512] = 0;

  // per-lane P base (bytes); step stride 8192B
  const char* pb = (const char*)P +
      (((size_t)blk * 512) * 32 + ((size_t)w * 4 + g)) * 256 + ln * 16;

  // LDS byte offsets (XOR swizzle on bits 4-6; offsets < 4096)
  int swz = (ln & 7) << 4;
  int rdoff[4];
#pragma unroll
  for (int ks = 0; ks < 4; ks++) rdoff[ks] = (ln * 256 + ks * 64 + g * 16) ^ swz;
  int wroff = (ln * 256 + w * 32 + g * 8) ^ swz;
  char* hb = (char*)&sH[0][0];

  const f32x4 Z4 = {0.f, 0.f, 0.f, 0.f};
  f32x4 P0, P1, P2;

#define PSTEP(S, PU, PN, PAR, DOLOAD)                                        \
  do {                                                                       \
    f16x8 Hf[4];                                                             \
    _Pragma("unroll") for (int ks = 0; ks < 4; ks++)                         \
        Hf[ks] = *(const f16x8*)(hb + (PAR)*4096 + rdoff[ks]);               \
    if (DOLOAD) { PN = *(const f32x4*)(pb + (size_t)((S) + 2) * 8192); }     \
    f32x4 preA = PU;                                                         \
    _Pragma("unroll") for (int ks = 0; ks < 4; ks++)                         \
        preA = MFMAH(wh[ks], Hf[ks], preA);                                  \
    f32x4 preB = Z4;                                                         \
    _Pragma("unroll") for (int ks = 0; ks < 4; ks++)                         \
        preB = MFMAH(wl[ks], Hf[ks], preB);                                  \
    _Pragma("unroll") for (int r = 0; r < 4; r++)                            \
        preA[r] = fmaf(preB[r], 0.0009765625f, preA[r]);                     \
    {                                                                        \
      float t0 = ftanh(preA[0]), t1 = ftanh(preA[1]);                        \
      float t2 = ftanh(preA[2]), t3 = ftanh(preA[3]);                        \
      uint2 hv = {pk16(t0, t1), pk16(t2, t3)};                               \
      *(uint2*)(hb + ((PAR) ^ 1) * 4096 + wroff) = hv;                       \
    }                                                                        \
    BAR();                                                                   \
  } while (0)

  P0 = *(const f32x4*)(pb);
  P1 = *(const f32x4*)(pb + 8192);
  BAR();  // H zeros visible

#pragma unroll 1
  for (int s6 = 0; s6 < 504; s6 += 6) {
    PSTEP(s6 + 0, P0, P2, 0, 1);
    PSTEP(s6 + 1, P1, P0, 1, 1);
    PSTEP(s6 + 2, P2, P1, 0, 1);
    PSTEP(s6 + 3, P0, P2, 1, 1);
    PSTEP(s6 + 4, P1, P0, 0, 1);
    PSTEP(s6 + 5, P2, P1, 1, 1);
  }
  PSTEP(504, P0, P2, 0, 1);
  PSTEP(505, P1, P0, 1, 1);
  PSTEP(506, P2, P1, 0, 1);
  PSTEP(507, P0, P2, 1, 1);
  PSTEP(508, P1, P0, 0, 1);
  PSTEP(509, P2, P1, 1, 1);
  PSTEP(510, P0, P2, 0, 0);
  PSTEP(511, P1, P0, 1, 0);

  // ---- MLP head: h_512 (f16) in sH[0] ----
  {
    int p = tid >> 5, q = tid & 31;
    if (q < F_DIM) {
      float acc = fc1_b[e * F_DIM + q];
      const float* w1 = fc1_w + (size_t)e * (F_DIM * 128) + q * 128;
      for (int k = 0; k < 128; k++) {
        int off = (p * 256 + k * 2) ^ ((p & 7) << 4);
        float h = (float)(*(const _Float16*)(hb + off));
        acc = fmaf(h, w1[k], acc);
      }
      sZ[p * F_DIM + q] = ftanh(acc);
    }
  }
  __syncthreads();
  if (tid < BM) {
    float acc = fc2_b[e];
#pragma unroll
    for (int f = 0; f < F_DIM; f++)
      acc += sZ[tid * F_DIM + f] * fc2_w[e * F_DIM + f];
    if (tid < nr) outp[p0 + tid] = acc;
  }
#undef PSTEP
}

// ---------------- Kernel 4: weighted combine ----------------
__global__ void k_combine(const float* __restrict__ sel_g,
                          const int* __restrict__ pair_of,
                          const float* __restrict__ outp,
                          float* __restrict__ y) {
  int b = blockIdx.x * blockDim.x + threadIdx.x;
  if (b < B_SZ)
    y[b] = sel_g[2 * b] * outp[pair_of[2 * b]] +
           sel_g[2 * b + 1] * outp[pair_of[2 * b + 1]];
}

extern "C" void kernel_launch(void* const* d_in, const int* in_sizes, int n_in,
                              void* d_out, int out_size, void* d_ws,
                              size_t ws_size, hipStream_t stream) {
  (void)in_sizes; (void)n_in; (void)out_size; (void)ws_size;
  const float* x      = (const float*)d_in[0];
  const float* w_gate = (const float*)d_in[1];
  const float* W_ih   = (const float*)d_in[2];
  const float* W_hh   = (const float*)d_in[3];
  const float* b_ih   = (const float*)d_in[4];
  const float* b_hh   = (const float*)d_in[5];
  const float* fc1_w  = (const float*)d_in[6];
  const float* fc1_b  = (const float*)d_in[7];
  const float* fc2_w  = (const float*)d_in[8];
  const float* fc2_b  = (const float*)d_in[9];
  float* out = (float*)d_out;  // [0..511] = y, [512] = loss

  float* logits = (float*)d_ws;            // 4096 f32
  float* sel_g  = logits + 4096;           // 1024 f32
  int*   pair_b = (int*)(sel_g + 1024);    // 1024 i32
  int*   pair_of= pair_b + 1024;           // 1024 i32
  int*   blk_e  = pair_of + 1024;          // 128 i32
  int*   blk_p0 = blk_e + 128;             // 128 i32
  int*   blk_nr = blk_p0 + 128;            // 128 i32
  int*   nblk   = blk_nr + 128;            // 8 i32
  float* outp   = (float*)(nblk + 8);      // 1024 f32
  unsigned short* Wih_h = (unsigned short*)((char*)d_ws + 65536);  // 256 KB
  unsigned short* Wih_l = Wih_h + 131072;                          // 256 KB
  float* P = (float*)((char*)d_ws + 65536 + 524288);  // 284 MiB (ws>=302MB proven r5)

  k_wsplit<<<64, 256, 0, stream>>>(W_ih, Wih_h, Wih_l);
  k_mean_logits<<<B_SZ, 512, 0, stream>>>(x, w_gate, logits);
  k_gate<<<1, 512, 0, stream>>>(logits, sel_g, pair_b, pair_of, blk_e, blk_p0,
                                blk_nr, nblk, out + 512);
  k_xproj<<<MAXBLK * SGRP, 512, 0, stream>>>(x, Wih_h, Wih_l, b_ih, b_hh,
                                             pair_b, blk_e, blk_p0, blk_nr,
                                             nblk, P);
  k_rnn_p<<<MAXBLK, 512, 0, stream>>>(P, W_hh, fc1_w, fc1_b, fc2_w, fc2_b,
                                      blk_e, blk_p0, blk_nr, nblk, outp);
  k_combine<<<2, 256, 0, stream>>>(sel_g, pair_of, outp, out);
}

// Round 8
// 346.088 us; speedup vs baseline: 1.5675x; 1.5675x over previous
//
#include <hip/hip_runtime.h>
#include <math.h>

#define B_SZ 512
#define S_SZ 512
#define E_NUM 8
#define F_DIM 20
#define BM 16          // pairs per RNN block (full MFMA N-tile)
#define MAXBLK 71      // max sum_e ceil(cnt_e/16) = 71

typedef __attribute__((ext_vector_type(8))) _Float16 f16x8;
typedef __attribute__((ext_vector_type(4))) float f32x4;
#define MFMAH(a, b, c) __builtin_amdgcn_mfma_f32_16x16x32_f16(a, b, c, 0, 0, 0)

// pack two f32 -> f16 pair (RNE) in one dword
__device__ __forceinline__ unsigned pk16(float a, float b) {
  _Float16 ha = (_Float16)a, hb = (_Float16)b;
  unsigned short ua = __builtin_bit_cast(unsigned short, ha);
  unsigned short ub = __builtin_bit_cast(unsigned short, hb);
  return (unsigned)ua | ((unsigned)ub << 16);
}
__device__ __forceinline__ float ftanh(float x) {
  float e = __expf(x + x);  // +inf -> rcp(inf)=0 -> 1; -inf -> e=0 -> -1
  float r;
  asm("v_rcp_f32 %0, %1" : "=v"(r) : "v"(e + 1.0f));
  return fmaf(-2.0f, r, 1.0f);
}

// raw barrier: waits LDS ops only; global loads stay in flight
#define BAR() do {                                        \
  asm volatile("s_waitcnt lgkmcnt(0)" ::: "memory");      \
  __builtin_amdgcn_s_barrier();                           \
  asm volatile("" ::: "memory");                          \
} while (0)

// ------ Kernel 0: one-time W_ih f16 2-split (lo pre-scaled x1024) ------
__global__ __launch_bounds__(256) void k_wsplit16(
    const float* __restrict__ W, _Float16* __restrict__ Wh,
    _Float16* __restrict__ Wl) {
  int idx = (blockIdx.x * 256 + threadIdx.x) * 8;  // 64 blocks cover 131072
  float4 a = *(const float4*)(W + idx);
  float4 b = *(const float4*)(W + idx + 4);
  float v[8] = {a.x, a.y, a.z, a.w, b.x, b.y, b.z, b.w};
  f16x8 h, l;
#pragma unroll
  for (int j = 0; j < 8; j++) {
    _Float16 hh = (_Float16)v[j];
    h[j] = hh;
    l[j] = (_Float16)((v[j] - (float)hh) * 1024.0f);
  }
  *(f16x8*)(Wh + idx) = h;
  *(f16x8*)(Wl + idx) = l;
}

// ---------------- Kernel 1: x_mean + logits ----------------
__global__ __launch_bounds__(512) void k_mean_logits(
    const float* __restrict__ x, const float* __restrict__ w_gate,
    float* __restrict__ logits) {
  __shared__ float sm[512];
  __shared__ float xm[128];
  int b = blockIdx.x;
  int t = threadIdx.x;
  int i = t & 127, s0 = t >> 7;
  const float* xb = x + (size_t)b * (S_SZ * 128);
  float acc = 0.f;
  for (int s = s0; s < S_SZ; s += 4) acc += xb[s * 128 + i];
  sm[t] = acc;
  __syncthreads();
  if (t < 128)
    xm[t] = (sm[t] + sm[t + 128] + sm[t + 256] + sm[t + 384]) * (1.0f / 512.0f);
  __syncthreads();
  if (t < E_NUM) {
    float acc2 = 0.f;
    for (int ii = 0; ii < 128; ii++) acc2 += xm[ii] * w_gate[ii * E_NUM + t];
    logits[b * E_NUM + t] = acc2;
  }
}

// ------- Kernel 2: top-2 gates + CV^2 loss + expert compaction -------
__global__ __launch_bounds__(512) void k_gate(
    const float* __restrict__ logits, float* __restrict__ sel_g,
    int* __restrict__ pair_b, int* __restrict__ pair_of,
    int* __restrict__ blk_e, int* __restrict__ blk_p0,
    int* __restrict__ blk_nr, int* __restrict__ nblk,
    float* __restrict__ loss_out) {
  __shared__ float gmat[512][8];
  __shared__ int cnt[8], base[8], pos[8];
  __shared__ float imps[8];
  int t = threadIdx.x;
  if (t < 8) { cnt[t] = 0; pos[t] = 0; }
  float lv[8];
#pragma unroll
  for (int e = 0; e < 8; e++) {
    lv[e] = logits[t * 8 + e];
    gmat[t][e] = 0.f;
  }
  __syncthreads();
  float v0 = -INFINITY, v1 = -INFINITY;
  int i0 = 0, i1 = 0;
#pragma unroll
  for (int e = 0; e < 8; e++) {
    float v = lv[e];
    if (v > v0) { v1 = v0; i1 = i0; v0 = v; i0 = e; }
    else if (v > v1) { v1 = v; i1 = e; }
  }
  float ex = expf(v1 - v0);
  float inv = 1.0f / (1.0f + ex);
  float g0 = inv, g1 = ex * inv;
  gmat[t][i0] = g0;
  gmat[t][i1] = g1;
  atomicAdd(&cnt[i0], 1);
  atomicAdd(&cnt[i1], 1);
  sel_g[t * 2] = g0;
  sel_g[t * 2 + 1] = g1;
  __syncthreads();
  if (t == 0) {
    int o = 0;
    for (int e = 0; e < 8; e++) { base[e] = o; o += cnt[e]; }
    int nb = 0;
    for (int e = 0; e < 8; e++)
      for (int off = 0; off < cnt[e]; off += BM) {
        blk_e[nb] = e;
        blk_p0[nb] = base[e] + off;
        blk_nr[nb] = min(BM, cnt[e] - off);
        nb++;
      }
    *nblk = nb;
  }
  if (t < 8) {
    float s = 0.f;
    for (int bb = 0; bb < 512; bb++) s += gmat[bb][t];
    imps[t] = s;
  }
  __syncthreads();
  {
    int r = atomicAdd(&pos[i0], 1);
    int p = base[i0] + r;
    pair_b[p] = t;
    pair_of[t * 2] = p;
  }
  {
    int r = atomicAdd(&pos[i1], 1);
    int p = base[i1] + r;
    pair_b[p] = t;
    pair_of[t * 2 + 1] = p;
  }
  if (t == 0) {
    float mi = 0.f, ml = 0.f;
#pragma unroll
    for (int e = 0; e < 8; e++) { mi += imps[e]; ml += (float)cnt[e]; }
    mi *= 0.125f; ml *= 0.125f;
    float vi = 0.f, vl = 0.f;
#pragma unroll
    for (int e = 0; e < 8; e++) {
      float di = imps[e] - mi; vi += di * di;
      float dl = (float)cnt[e] - ml; vl += dl * dl;
    }
    vi *= (1.0f / 7.0f);
    vl *= (1.0f / 7.0f);
    loss_out[0] = 0.01f * (vi / (mi * mi + 1e-10f) + vl / (ml * ml + 1e-10f));
  }
}

// ---- Kernel 3: fused producer/consumer MoE-RNN ----
// waves 0-3: producers — stage x (f16) into a 4-slot LDS ring, compute
//   P[s] = W_ih·x_s + biases (f16 2-split W, single-f16 X) into 2-slot P ring.
// waves 4-7: consumers — h_{s+1} = tanh(P[s] + W_hh·h_s) (f16 2-split W_hh,
//   single-f16 H in LDS ping-pong). One raw barrier per step, lockstep.
__global__ __launch_bounds__(512, 2) void k_moe(
    const float* __restrict__ x, const _Float16* __restrict__ Wih_h,
    const _Float16* __restrict__ Wih_l, const float* __restrict__ W_hh,
    const float* __restrict__ b_ih, const float* __restrict__ b_hh,
    const float* __restrict__ fc1_w, const float* __restrict__ fc1_b,
    const float* __restrict__ fc2_w, const float* __restrict__ fc2_b,
    const int* __restrict__ pair_b, const int* __restrict__ blk_e,
    const int* __restrict__ blk_p0, const int* __restrict__ blk_nr,
    const int* __restrict__ nblk, float* __restrict__ outp) {
  __shared__ unsigned short sX[4][2048];  // f16 X ring, 4 x 4KB
  __shared__ float sP[2][2048];           // f32 P ring, 2 x 8KB
  __shared__ unsigned short sH[2][2048];  // f16 H ping-pong, 2 x 4KB
  __shared__ float sZ[BM * F_DIM];

  int blk = blockIdx.x;
  if (blk >= *nblk) return;
  int e = blk_e[blk], p0 = blk_p0[blk], nr = blk_nr[blk];
  int tid = threadIdx.x;
  int lane = tid & 63, g = lane >> 4, ln = lane & 15;
  int wv = tid >> 6;

  char* sxb = (char*)&sX[0][0];
  char* spb = (char*)&sP[0][0];
  char* shb = (char*)&sH[0][0];

  // zero H slot 0 (4KB)
  ((unsigned int*)shb)[tid] = 0;
  ((unsigned int*)shb)[tid + 512] = 0;

  // fragment-read offsets (shared geometry: 16 rows x 128 f16, XOR swizzle)
  int swz = (ln & 7) << 4;
  int rdoff[4];
#pragma unroll
  for (int ks = 0; ks < 4; ks++) rdoff[ks] = (ln * 256 + ks * 64 + g * 16) ^ swz;

  const f32x4 Z4 = {0.f, 0.f, 0.f, 0.f};

  if (wv < 4) {
    // ================== PRODUCER (M-tiles 2wv, 2wv+1) ==================
    int w = wv;
    f16x8 wih_h[2][4], wih_l[2][4];
#pragma unroll
    for (int m = 0; m < 2; m++) {
      int row = (2 * w + m) * 16 + ln;
      const _Float16* bh = Wih_h + (size_t)e * 16384 + row * 128 + g * 8;
      const _Float16* bl = Wih_l + (size_t)e * 16384 + row * 128 + g * 8;
#pragma unroll
      for (int ks = 0; ks < 4; ks++) {
        wih_h[m][ks] = *(const f16x8*)(bh + ks * 32);
        wih_l[m][ks] = *(const f16x8*)(bl + ks * 32);
      }
    }
    f32x4 biasv[2];
#pragma unroll
    for (int m = 0; m < 2; m++)
#pragma unroll
      for (int r = 0; r < 4; r++) {
        int h = (2 * w + m) * 16 + g * 4 + r;
        biasv[m][r] = b_ih[e * 128 + h] + b_hh[e * 128 + h];
      }
    int pwoff[2];
#pragma unroll
    for (int m = 0; m < 2; m++)
      pwoff[m] = (2 * w + m) * 1024 + g * 256 + ln * 16;

    // staging: lane handles row 4w+(lane>>4), elems k0..k0+7
    int srow = 4 * w + (lane >> 4);
    int k0 = (lane & 15) * 8;
    int sb = pair_b[p0 + (srow < nr ? srow : 0)];
    const char* xsrc = (const char*)x + (size_t)sb * (S_SZ * 512) + k0 * 4;
    int stoff = (srow * 256 + k0 * 2) ^ ((srow & 7) << 4);

    float4 xa0, xa1, xb0, xb1;

#define LDX(B0, B1, STEP)                                                    \
  do {                                                                       \
    B0 = *(const float4*)(xsrc + (size_t)(STEP) * 512);                      \
    B1 = *(const float4*)(xsrc + (size_t)(STEP) * 512 + 16);                 \
  } while (0)

#define STG(WS, B0, B1)                                                      \
  do {                                                                       \
    float v[8] = {B0.x, B0.y, B0.z, B0.w, B1.x, B1.y, B1.z, B1.w};           \
    f16x8 hx;                                                                \
    _Pragma("unroll") for (int j = 0; j < 8; j++) hx[j] = (_Float16)v[j];    \
    *(f16x8*)(sxb + ((WS) << 12) + stoff) = hx;                              \
  } while (0)

#define PRD(XS, PS)                                                          \
  do {                                                                       \
    f16x8 Xf[4];                                                             \
    _Pragma("unroll") for (int ks = 0; ks < 4; ks++)                         \
        Xf[ks] = *(const f16x8*)(sxb + ((XS) << 12) + rdoff[ks]);            \
    _Pragma("unroll") for (int m = 0; m < 2; m++) {                          \
      f32x4 pA = biasv[m];                                                   \
      _Pragma("unroll") for (int ks = 0; ks < 4; ks++)                       \
          pA = MFMAH(wih_h[m][ks], Xf[ks], pA);                              \
      f32x4 pB = Z4;                                                         \
      _Pragma("unroll") for (int ks = 0; ks < 4; ks++)                       \
          pB = MFMAH(wih_l[m][ks], Xf[ks], pB);                              \
      _Pragma("unroll") for (int r = 0; r < 4; r++)                          \
          pA[r] = fmaf(pB[r], 0.0009765625f, pA[r]);                         \
      *(f32x4*)(spb + ((PS) << 13) + pwoff[m]) = pA;                         \
    }                                                                        \
  } while (0)

    // prologue
    LDX(xa0, xa1, 0);
    LDX(xb0, xb1, 1);
    STG(0, xa0, xa1);
    STG(1, xb0, xb1);
    LDX(xa0, xa1, 2);
    LDX(xb0, xb1, 3);
    BAR();  // #1: X0,X1,H0 visible
    PRD(0, 0);           // P[0]
    STG(2, xa0, xa1);    // X[2]
    LDX(xa0, xa1, 4);
    BAR();  // #2: P0,X2 visible

    // main rounds r = 0..503
#pragma unroll 1
    for (int r4 = 0; r4 < 504; r4 += 4) {
      PRD(1, 1); STG(3, xb0, xb1); LDX(xb0, xb1, r4 + 5); BAR();
      PRD(2, 0); STG(0, xa0, xa1); LDX(xa0, xa1, r4 + 6); BAR();
      PRD(3, 1); STG(1, xb0, xb1); LDX(xb0, xb1, r4 + 7); BAR();
      PRD(0, 0); STG(2, xa0, xa1); LDX(xa0, xa1, r4 + 8); BAR();
    }
    // tail rounds r = 504..511
    PRD(1, 1); STG(3, xb0, xb1); LDX(xb0, xb1, 509); BAR();  // 504
    PRD(2, 0); STG(0, xa0, xa1); LDX(xa0, xa1, 510); BAR();  // 505
    PRD(3, 1); STG(1, xb0, xb1); LDX(xb0, xb1, 511); BAR();  // 506
    PRD(0, 0); STG(2, xa0, xa1); BAR();                      // 507
    PRD(1, 1); STG(3, xb0, xb1); BAR();                      // 508
    PRD(2, 0); BAR();                                        // 509
    PRD(3, 1); BAR();                                        // 510 -> P[511]
    BAR();                                                   // 511
#undef PRD
#undef STG
#undef LDX
  } else {
    // ================== CONSUMER (M-tiles 2w2, 2w2+1) ==================
    int w2 = wv - 4;
    f16x8 wh[2][4], wl[2][4];
#pragma unroll
    for (int m = 0; m < 2; m++) {
      int row = (2 * w2 + m) * 16 + ln;
      const float* bh = W_hh + (size_t)e * 16384 + row * 128 + g * 8;
#pragma unroll
      for (int ks = 0; ks < 4; ks++) {
        float4 a = *(const float4*)(bh + ks * 32);
        float4 b = *(const float4*)(bh + ks * 32 + 4);
        float v[8] = {a.x, a.y, a.z, a.w, b.x, b.y, b.z, b.w};
        f16x8 h, l;
#pragma unroll
        for (int j = 0; j < 8; j++) {
          _Float16 hh = (_Float16)v[j];
          h[j] = hh;
          l[j] = (_Float16)((v[j] - (float)hh) * 1024.0f);
        }
        wh[m][ks] = h;
        wl[m][ks] = l;
      }
    }
    int proff[2], wroff[2];
#pragma unroll
    for (int m = 0; m < 2; m++) {
      proff[m] = (2 * w2 + m) * 1024 + g * 256 + ln * 16;
      wroff[m] = (ln * 256 + (2 * w2 + m) * 32 + g * 8) ^ swz;
    }

#define CRD(RS)                                                              \
  do {                                                                       \
    f16x8 Hf[4];                                                             \
    _Pragma("unroll") for (int ks = 0; ks < 4; ks++)                         \
        Hf[ks] = *(const f16x8*)(shb + (RS) * 4096 + rdoff[ks]);             \
    _Pragma("unroll") for (int m = 0; m < 2; m++) {                          \
      f32x4 preA = *(const f32x4*)(spb + ((RS) << 13) + proff[m]);           \
      _Pragma("unroll") for (int ks = 0; ks < 4; ks++)                       \
          preA = MFMAH(wh[m][ks], Hf[ks], preA);                             \
      f32x4 preB = Z4;                                                       \
      _Pragma("unroll") for (int ks = 0; ks < 4; ks++)                       \
          preB = MFMAH(wl[m][ks], Hf[ks], preB);                             \
      _Pragma("unroll") for (int r = 0; r < 4; r++)                          \
          preA[r] = fmaf(preB[r], 0.0009765625f, preA[r]);                   \
      float t0 = ftanh(preA[0]), t1 = ftanh(preA[1]);                        \
      float t2 = ftanh(preA[2]), t3 = ftanh(preA[3]);                        \
      uint2 hv = {pk16(t0, t1), pk16(t2, t3)};                               \
      *(uint2*)(shb + ((RS) ^ 1) * 4096 + wroff[m]) = hv;                    \
    }                                                                        \
  } while (0)

    BAR();  // #1
    BAR();  // #2
#pragma unroll 1
    for (int it = 0; it < 128; it++) {
      CRD(0); BAR();
      CRD(1); BAR();
      CRD(0); BAR();
      CRD(1); BAR();
    }
#undef CRD
  }

  // ---- MLP head: h_512 (f16) in sH slot 0 ----
  {
    int p = tid >> 5, q = tid & 31;
    if (q < F_DIM) {
      float acc = fc1_b[e * F_DIM + q];
      const float* w1 = fc1_w + (size_t)e * (F_DIM * 128) + q * 128;
      for (int k = 0; k < 128; k++) {
        int off = (p * 256 + k * 2) ^ ((p & 7) << 4);
        float h = (float)(*(const _Float16*)(shb + off));
        acc = fmaf(h, w1[k], acc);
      }
      sZ[p * F_DIM + q] = ftanh(acc);
    }
  }
  __syncthreads();
  if (tid < BM) {
    float acc = fc2_b[e];
#pragma unroll
    for (int f = 0; f < F_DIM; f++)
      acc += sZ[tid * F_DIM + f] * fc2_w[e * F_DIM + f];
    if (tid < nr) outp[p0 + tid] = acc;
  }
}

// ---------------- Kernel 4: weighted combine ----------------
__global__ void k_combine(const float* __restrict__ sel_g,
                          const int* __restrict__ pair_of,
                          const float* __restrict__ outp,
                          float* __restrict__ y) {
  int b = blockIdx.x * blockDim.x + threadIdx.x;
  if (b < B_SZ)
    y[b] = sel_g[2 * b] * outp[pair_of[2 * b]] +
           sel_g[2 * b + 1] * outp[pair_of[2 * b + 1]];
}

extern "C" void kernel_launch(void* const* d_in, const int* in_sizes, int n_in,
                              void* d_out, int out_size, void* d_ws,
                              size_t ws_size, hipStream_t stream) {
  (void)in_sizes; (void)n_in; (void)out_size; (void)ws_size;
  const float* x      = (const float*)d_in[0];
  const float* w_gate = (const float*)d_in[1];
  const float* W_ih   = (const float*)d_in[2];
  const float* W_hh   = (const float*)d_in[3];
  const float* b_ih   = (const float*)d_in[4];
  const float* b_hh   = (const float*)d_in[5];
  const float* fc1_w  = (const float*)d_in[6];
  const float* fc1_b  = (const float*)d_in[7];
  const float* fc2_w  = (const float*)d_in[8];
  const float* fc2_b  = (const float*)d_in[9];
  float* out = (float*)d_out;  // [0..511] = y, [512] = loss

  float* logits = (float*)d_ws;            // 4096 f32
  float* sel_g  = logits + 4096;           // 1024 f32
  int*   pair_b = (int*)(sel_g + 1024);    // 1024 i32
  int*   pair_of= pair_b + 1024;           // 1024 i32
  int*   blk_e  = pair_of + 1024;          // 128 i32
  int*   blk_p0 = blk_e + 128;             // 128 i32
  int*   blk_nr = blk_p0 + 128;            // 128 i32
  int*   nblk   = blk_nr + 128;            // 8 i32
  float* outp   = (float*)(nblk + 8);      // 1024 f32
  _Float16* Wih_h = (_Float16*)((char*)d_ws + 65536);  // 256 KB
  _Float16* Wih_l = Wih_h + 131072;                    // 256 KB

  k_wsplit16<<<64, 256, 0, stream>>>(W_ih, Wih_h, Wih_l);
  k_mean_logits<<<B_SZ, 512, 0, stream>>>(x, w_gate, logits);
  k_gate<<<1, 512, 0, stream>>>(logits, sel_g, pair_b, pair_of, blk_e, blk_p0,
                                blk_nr, nblk, out + 512);
  k_moe<<<MAXBLK, 512, 0, stream>>>(x, Wih_h, Wih_l, W_hh, b_ih, b_hh, fc1_w,
                                    fc1_b, fc2_w, fc2_b, pair_b, blk_e,
                                    blk_p0, blk_nr, nblk, outp);
  k_combine<<<2, 256, 0, stream>>>(sel_g, pair_of, outp, out);
}